// Round 2
// baseline (23250.107 us; speedup 1.0000x reference)
//
#include <hip/hip_runtime.h>
#include <hip/hip_bf16.h>
#include <hip/hip_cooperative_groups.h>

namespace cg = cooperative_groups;

#define BB 64
#define VV 2048
#define ENCD 128
#define TT 100
#define EMBD 256
#define DECD 512
#define ATTD 256
#define NVOCAB 29

typedef unsigned int u32;
typedef unsigned short u16;

__device__ __forceinline__ float sigf(float x) { return 1.0f / (1.0f + __expf(-x)); }

// ---------------- one-time init kernels ----------------

// Transpose W_dec [ATT][DEC] -> W_decT [DEC][ATT], W_beta [ENC][DEC] -> W_betaT [DEC][ENC]
__global__ __launch_bounds__(256) void k_transpose(const float* __restrict__ W_dec,
                                                   const float* __restrict__ W_beta,
                                                   float* __restrict__ W_decT,
                                                   float* __restrict__ W_betaT) {
    int i = blockIdx.x * 256 + threadIdx.x;
    if (i < DECD * ATTD) {
        int l = i / ATTD, a = i % ATTD;
        W_decT[i] = W_dec[a * DECD + l];
    }
    int j = i - DECD * ATTD;
    if (j >= 0 && j < DECD * ENCD) {
        int l = j / ENCD, e = j % ENCD;
        W_betaT[j] = W_beta[e * DECD + l];
    }
}

// enc_attT[b][a][v] = bf16( enc[b][v][:] . W_enc[a][:] + b_enc[a] )
// 8 accumulators/thread: each LDS read feeds 8 FMAs (was 1) -> LDS traffic /8.
__global__ __launch_bounds__(256) void k_enc_att(const float* __restrict__ enc,
                                                 const float* __restrict__ W_enc,
                                                 const float* __restrict__ b_enc,
                                                 u16* __restrict__ enc_attT) {
    __shared__ float tile[64][ENCD + 1];   // +1 pad: conflict-free column reads
    int b = blockIdx.y, v0 = blockIdx.x * 64;
    int t = threadIdx.x;
    const float* src = enc + ((size_t)b * VV + v0) * ENCD;
    for (int i = t; i < 64 * ENCD; i += 256) tile[i >> 7][i & 127] = src[i];
    __syncthreads();
    int vl = t & 63, ag = t >> 6;          // ag wave-uniform -> W_enc loads go scalar
    for (int ao = 0; ao < 8; ao++) {
        int a0 = ag * 64 + ao * 8;
        float acc[8];
        #pragma unroll
        for (int j = 0; j < 8; j++) acc[j] = b_enc[a0 + j];
        const float* w = W_enc + (size_t)a0 * ENCD;
        for (int k = 0; k < ENCD; k++) {
            float x = tile[vl][k];
            #pragma unroll
            for (int j = 0; j < 8; j++) acc[j] = fmaf(x, w[j * ENCD + k], acc[j]);
        }
        #pragma unroll
        for (int j = 0; j < 8; j++) {
            u32 u = __float_as_uint(acc[j]);
            u += 0x7fffu + ((u >> 16) & 1u);   // round-to-nearest-even bf16
            enc_attT[((size_t)b * ATTD + a0 + j) * VV + v0 + vl] = (u16)(u >> 16);
        }
    }
}

// mean_enc -> h0,c0 -> dec_att0, gate0, xT(emb0 + h0 rows), lengths output
__global__ __launch_bounds__(512) void k_init(const float* __restrict__ enc,
                                              const int* __restrict__ lens,
                                              const int* __restrict__ captions,
                                              const float* __restrict__ emb_W,
                                              const float* __restrict__ W_init_h,
                                              const float* __restrict__ b_init_h,
                                              const float* __restrict__ W_init_c,
                                              const float* __restrict__ b_init_c,
                                              const float* __restrict__ W_decT,
                                              const float* __restrict__ b_dec,
                                              const float* __restrict__ W_betaT,
                                              const float* __restrict__ b_beta,
                                              float* __restrict__ c0,
                                              float* __restrict__ xT,
                                              float* __restrict__ dec_att,
                                              float* __restrict__ gate,
                                              float* __restrict__ out_len) {
    __shared__ float part[512];
    __shared__ float mean[ENCD];
    __shared__ float h_s[DECD];
    int b = blockIdx.x, t = threadIdx.x;
    int e = t & 127, ch = t >> 7;
    float s = 0.f;
    const float* rowb = enc + (size_t)b * VV * ENCD;
    for (int v = ch * 512; v < ch * 512 + 512; v++) s += rowb[(size_t)v * ENCD + e];
    part[t] = s;
    __syncthreads();
    if (ch == 0) mean[e] = (part[e] + part[128 + e] + part[256 + e] + part[384 + e]) * (1.0f / VV);
    __syncthreads();
    {
        int d = t;
        float hh = b_init_h[d], cc = b_init_c[d];
        for (int k = 0; k < ENCD; k++) {
            hh = fmaf(mean[k], W_init_h[d * ENCD + k], hh);
            cc = fmaf(mean[k], W_init_c[d * ENCD + k], cc);
        }
        c0[b * DECD + d] = cc;
        h_s[d] = hh;
        xT[(384 + d) * BB + b] = hh;       // h part of unified x
    }
    __syncthreads();
    if (t < ATTD) {
        float s2 = b_dec[t];
        for (int l = 0; l < DECD; l++) s2 = fmaf(h_s[l], W_decT[l * ATTD + t], s2);
        dec_att[b * ATTD + t] = s2;
    } else if (t < ATTD + ENCD) {
        int ee = t - ATTD;
        float s2 = b_beta[ee];
        for (int l = 0; l < DECD; l++) s2 = fmaf(h_s[l], W_betaT[l * ENCD + ee], s2);
        gate[b * ENCD + ee] = sigf(s2);
    } else {
        int k = t - 384;
        int cap = captions[b * TT + 0];
        xT[k * BB + b] = emb_W[cap * EMBD + k];
        xT[(k + 128) * BB + b] = emb_W[cap * EMBD + k + 128];
    }
    if (t == 0) out_len[b] = (float)lens[b];
}

// ---------------- persistent cooperative step kernel ----------------

struct P {
    const float* enc;
    const int*   captions;
    const int*   lens;
    const float* emb_W;
    const float* w_full;
    const float* W_ih;
    const float* W_hh;
    const float* b_ih;
    const float* b_hh;
    const float* W_final;
    const float* b_final;
    const float* b_dec;
    const float* b_beta;
    const u16*   enc_attT;
    const float* W_decT;
    const float* W_betaT;
    float* escore;
    float* denom;      // [TT][BB], zero-init
    float* awe;        // [TT][BB][ENC], zero-init (unnormalized)
    float* dec_att;    // [BB][ATT]
    float* gate;       // [BB][ENC]
    float* xT;         // [896][BB]
    float* gates_part; // [7][BB][2048]
    float* c0;         // ping
    float* c1;         // pong
    float* preds;
    float* alphas;
};

__global__ __launch_bounds__(256, 2) void k_step(P p) {
    cg::grid_group grid = cg::this_grid();
    __shared__ float sm[BB][ENCD + 1];   // phase2 gawe; 129 % 32 == 1 -> conflict-free
    __shared__ float sd[ATTD];
    __shared__ float sw[ATTD];
    __shared__ float esh[256];
    __shared__ float red[256];
    __shared__ float h_s[DECD];
    int blk = blockIdx.x, t = threadIdx.x;
    int lane = t & 63, wv = t >> 6;

    for (int ts = 0; ts < TT; ts++) {
        // ---- phase 1: scores -> exp -> denom + unnormalized awe (8 chunks of 256 v per b)
        {
            int b = blk >> 3, v0 = (blk & 7) * 256;
            if (ts < p.lens[b]) {
                sd[t] = p.dec_att[b * ATTD + t];
                sw[t] = p.w_full[t];
                __syncthreads();
                const u16* sp = p.enc_attT + (size_t)b * ATTD * VV + v0 + t;
                float s = 0.f;
                #pragma unroll 16
                for (int a = 0; a < ATTD; a++) {
                    float x = __uint_as_float((u32)sp[(size_t)a * VV] << 16) + sd[a];
                    s = fmaf(fmaxf(x, 0.f), sw[a], s);
                }
                float e = __expf(s);        // b_full dropped (softmax shift-invariant); |s|<~3
                p.escore[b * VV + v0 + t] = e;
                esh[t] = e;
                float ss = e;
                for (int o = 32; o > 0; o >>= 1) ss += __shfl_down(ss, o);
                if (lane == 0) red[wv] = ss;
                __syncthreads();
                if (t == 0) atomicAdd(&p.denom[ts * BB + b], red[0] + red[1] + red[2] + red[3]);
                int e2 = t & 127, half = t >> 7;
                const float* encb = p.enc + ((size_t)b * VV + v0) * ENCD + e2;
                float acc = 0.f;
                #pragma unroll 8
                for (int v = half; v < 256; v += 2)
                    acc = fmaf(esh[v], encb[(size_t)v * ENCD], acc);
                atomicAdd(&p.awe[((size_t)ts * BB + b) * ENCD + e2], acc);
            }
        }
        grid.sync();

        // ---- phase 2: LSTM gate partials (448 items) + alphas (64 blocks)
        {
            if (blk < 448) {
                int gt = blk & 63, kc = blk >> 6;       // kc 0..6, K chunks of 128
                int gbase = gt * 32 + wv * 8;
                float acc[8];
                #pragma unroll
                for (int j = 0; j < 8; j++)
                    acc[j] = (kc == 0) ? (p.b_ih[gbase + j] + p.b_hh[gbase + j]) : 0.f;
                if (kc == 2) {                           // gated-awe columns 256..383
                    if (t < BB) {
                        float dn = p.denom[ts * BB + t];
                        red[t] = dn > 0.f ? 1.f / dn : 0.f;   // 0 for inactive b (gates unused)
                    }
                    __syncthreads();
                    for (int i = t; i < BB * ENCD; i += 256) {
                        int bb = i >> 7, ee = i & 127;
                        sm[bb][ee] = p.gate[bb * ENCD + ee] *
                                     p.awe[((size_t)ts * BB + bb) * ENCD + ee] * red[bb];
                    }
                    __syncthreads();
                    for (int kk = 0; kk < ENCD; kk++) {
                        float xv = sm[lane][kk];
                        #pragma unroll
                        for (int j = 0; j < 8; j++)
                            acc[j] = fmaf(xv, p.W_ih[(gbase + j) * 384 + 256 + kk], acc[j]);
                    }
                } else if (kc < 2) {                     // emb columns 0..255
                    int k0 = kc * 128;
                    for (int kk = 0; kk < 128; kk++) {
                        float xv = p.xT[(k0 + kk) * BB + lane];
                        #pragma unroll
                        for (int j = 0; j < 8; j++)
                            acc[j] = fmaf(xv, p.W_ih[(gbase + j) * 384 + k0 + kk], acc[j]);
                    }
                } else {                                 // h columns (W_hh)
                    int k0 = kc * 128;                   // 384..768
                    const float* Wh = p.W_hh + (k0 - 384);
                    for (int kk = 0; kk < 128; kk++) {
                        float xv = p.xT[(k0 + kk) * BB + lane];
                        #pragma unroll
                        for (int j = 0; j < 8; j++)
                            acc[j] = fmaf(xv, Wh[(gbase + j) * DECD + kk], acc[j]);
                    }
                }
                // [kc][b][g] layout -> phase3 reads coalesced over g
                float4* o4 = (float4*)(p.gates_part + ((size_t)kc * BB + lane) * 2048 + gbase);
                o4[0] = make_float4(acc[0], acc[1], acc[2], acc[3]);
                o4[1] = make_float4(acc[4], acc[5], acc[6], acc[7]);
            } else {
                int b2 = blk - 448;
                if (ts < p.lens[b2]) {
                    float inv = 1.f / p.denom[ts * BB + b2];
                    size_t obase = ((size_t)b2 * TT + ts) * VV;
                    const float* es = p.escore + b2 * VV;
                    for (int i = t; i < VV; i += 256)
                        p.alphas[obase + i] = es[i] * inv;
                }
            }
        }
        grid.sync();

        // ---- phase 3: cell + preds + next-step dec_att/gate/emb (8 parts per b)
        {
            int b = blk >> 3, part = blk & 7;
            if (ts < p.lens[b]) {
                const float* cin = (ts & 1) ? p.c1 : p.c0;   // ping-pong: no RAW race across parts
                float* cout      = (ts & 1) ? p.c0 : p.c1;
                #pragma unroll
                for (int r = 0; r < 2; r++) {
                    int d = t + r * 256;
                    float gi = 0.f, gf = 0.f, gg = 0.f, go = 0.f;
                    #pragma unroll
                    for (int kc = 0; kc < 7; kc++) {
                        const float* gp = p.gates_part + ((size_t)kc * BB + b) * 2048;
                        gi += gp[d]; gf += gp[512 + d]; gg += gp[1024 + d]; go += gp[1536 + d];
                    }
                    gi = sigf(gi); gf = sigf(gf); go = sigf(go); gg = tanhf(gg);
                    float cn = fmaf(gf, cin[b * DECD + d], gi * gg);
                    float hn = go * tanhf(cn);
                    h_s[d] = hn;
                    if (part == 0) {
                        cout[b * DECD + d] = cn;
                        p.xT[(384 + d) * BB + b] = hn;
                    }
                }
                __syncthreads();
                if (part == 0) {                          // emb staging for ts+1
                    if (ts + 1 < TT) {
                        int cap = p.captions[b * TT + ts + 1];
                        p.xT[t * BB + b] = p.emb_W[cap * EMBD + t];
                    }
                } else if (part <= 4) {                   // dec_att, 64-a slice, K split 4 ways
                    int a0 = (part - 1) * 64;
                    int a = a0 + (t & 63), kq = wv;
                    float s = 0.f;
                    const float* wd = p.W_decT + (size_t)kq * 128 * ATTD + a;
                    #pragma unroll 4
                    for (int l = 0; l < 128; l++)
                        s = fmaf(h_s[kq * 128 + l], wd[(size_t)l * ATTD], s);
                    red[t] = s;
                    __syncthreads();
                    if (t < 64)
                        p.dec_att[b * ATTD + a0 + t] =
                            red[t] + red[t + 64] + red[t + 128] + red[t + 192] + p.b_dec[a0 + t];
                } else if (part <= 6) {                   // gate, 64-e slice
                    int e0 = (part - 5) * 64;
                    int e = e0 + (t & 63), kq = wv;
                    float s = 0.f;
                    const float* wb = p.W_betaT + (size_t)kq * 128 * ENCD + e;
                    #pragma unroll 4
                    for (int l = 0; l < 128; l++)
                        s = fmaf(h_s[kq * 128 + l], wb[(size_t)l * ENCD], s);
                    red[t] = s;
                    __syncthreads();
                    if (t < 64)
                        p.gate[b * ENCD + e0 + t] =
                            sigf(red[t] + red[t + 64] + red[t + 128] + red[t + 192] + p.b_beta[e0 + t]);
                } else {                                  // predictions (29 vocab, K=512)
                    for (int j = wv; j < NVOCAB; j += 4) {
                        float s = 0.f;
                        #pragma unroll
                        for (int i = 0; i < 8; i++)
                            s = fmaf(h_s[lane + 64 * i], p.W_final[j * DECD + lane + 64 * i], s);
                        for (int o = 32; o > 0; o >>= 1) s += __shfl_down(s, o);
                        if (lane == 0)
                            p.preds[((size_t)b * TT + ts) * NVOCAB + j] = s + p.b_final[j];
                    }
                }
            }
        }
        grid.sync();
    }
}

extern "C" void kernel_launch(void* const* d_in, const int* in_sizes, int n_in,
                              void* d_out, int out_size, void* d_ws, size_t ws_size,
                              hipStream_t stream) {
    const float* enc      = (const float*)d_in[0];
    const int*   captions = (const int*)d_in[1];
    const int*   lens     = (const int*)d_in[2];
    const float* emb_W    = (const float*)d_in[3];
    const float* W_enc    = (const float*)d_in[4];
    const float* b_enc    = (const float*)d_in[5];
    const float* W_dec    = (const float*)d_in[6];
    const float* b_dec    = (const float*)d_in[7];
    const float* w_full   = (const float*)d_in[8];
    // d_in[9] b_full: unused — softmax is shift-invariant
    const float* W_ih     = (const float*)d_in[10];
    const float* b_ih     = (const float*)d_in[11];
    const float* W_hh     = (const float*)d_in[12];
    const float* b_hh     = (const float*)d_in[13];
    const float* W_init_h = (const float*)d_in[14];
    const float* b_init_h = (const float*)d_in[15];
    const float* W_init_c = (const float*)d_in[16];
    const float* b_init_c = (const float*)d_in[17];
    const float* W_beta   = (const float*)d_in[18];
    const float* b_beta   = (const float*)d_in[19];
    const float* W_final  = (const float*)d_in[20];
    const float* b_final  = (const float*)d_in[21];

    float* preds   = (float*)d_out;                      // [B][T][VOCAB]
    float* alphas  = preds + (size_t)BB * TT * NVOCAB;   // [B][T][V]
    float* out_len = alphas + (size_t)BB * TT * VV;      // [B] (written as float)

    char* ws = (char*)d_ws;
    size_t off = 0;
    auto alloc = [&](size_t bytes) {
        char* p = ws + off;
        off += (bytes + 255) & ~(size_t)255;
        return p;
    };
    u16*   enc_attT   = (u16*)  alloc((size_t)BB * ATTD * VV * sizeof(u16));   // 67 MB
    float* escore     = (float*)alloc((size_t)BB * VV * sizeof(float));
    char*  zbase      = ws + off;                                              // zeroed region start
    float* denom      = (float*)alloc((size_t)TT * BB * sizeof(float));
    float* awe        = (float*)alloc((size_t)TT * BB * ENCD * sizeof(float));
    size_t zbytes     = (size_t)((ws + off) - zbase);
    float* dec_att    = (float*)alloc((size_t)BB * ATTD * sizeof(float));
    float* gate       = (float*)alloc((size_t)BB * ENCD * sizeof(float));
    float* xT         = (float*)alloc((size_t)896 * BB * sizeof(float));
    float* gates_part = (float*)alloc((size_t)7 * BB * 2048 * sizeof(float));
    float* c0         = (float*)alloc((size_t)BB * DECD * sizeof(float));
    float* c1         = (float*)alloc((size_t)BB * DECD * sizeof(float));
    float* W_decT     = (float*)alloc((size_t)DECD * ATTD * sizeof(float));
    float* W_betaT    = (float*)alloc((size_t)DECD * ENCD * sizeof(float));

    // masked (b,t) outputs must be exactly 0; atomic targets must start at 0
    hipMemsetAsync(d_out, 0, (size_t)out_size * sizeof(float), stream);
    hipMemsetAsync(zbase, 0, zbytes, stream);

    k_transpose<<<768, 256, 0, stream>>>(W_dec, W_beta, W_decT, W_betaT);
    k_enc_att<<<dim3(VV / 64, BB), 256, 0, stream>>>(enc, W_enc, b_enc, enc_attT);
    k_init<<<BB, 512, 0, stream>>>(enc, lens, captions, emb_W, W_init_h, b_init_h,
                                   W_init_c, b_init_c, W_decT, b_dec, W_betaT, b_beta,
                                   c0, xT, dec_att, gate, out_len);

    P pv;
    pv.enc = enc; pv.captions = captions; pv.lens = lens; pv.emb_W = emb_W;
    pv.w_full = w_full; pv.W_ih = W_ih; pv.W_hh = W_hh; pv.b_ih = b_ih; pv.b_hh = b_hh;
    pv.W_final = W_final; pv.b_final = b_final; pv.b_dec = b_dec; pv.b_beta = b_beta;
    pv.enc_attT = enc_attT; pv.W_decT = W_decT; pv.W_betaT = W_betaT;
    pv.escore = escore; pv.denom = denom; pv.awe = awe; pv.dec_att = dec_att;
    pv.gate = gate; pv.xT = xT; pv.gates_part = gates_part; pv.c0 = c0; pv.c1 = c1;
    pv.preds = preds; pv.alphas = alphas;
    void* args[] = { (void*)&pv };
    hipLaunchCooperativeKernel((const void*)k_step, dim3(512), dim3(256), args, 0, stream);
}

// Round 3
// 7303.700 us; speedup vs baseline: 3.1833x; 3.1833x over previous
//
#include <hip/hip_runtime.h>
#include <hip/hip_bf16.h>

#define BB 64
#define VV 2048
#define ENCD 128
#define TT 100
#define EMBD 256
#define DECD 512
#define ATTD 256
#define NVOCAB 29

typedef unsigned int u32;
typedef unsigned short u16;

__device__ __forceinline__ float sigf(float x) { return 1.0f / (1.0f + __expf(-x)); }
__device__ __forceinline__ u16 to_bf16(float f) {
    u32 u = __float_as_uint(f);
    u += 0x7fffu + ((u >> 16) & 1u);       // round-to-nearest-even
    return (u16)(u >> 16);
}

// ---------------- one-time init kernels ----------------

// Transpose W_dec [ATT][DEC] -> W_decT [DEC][ATT], W_beta [ENC][DEC] -> W_betaT [DEC][ENC]
__global__ __launch_bounds__(256) void k_transpose(const float* __restrict__ W_dec,
                                                   const float* __restrict__ W_beta,
                                                   float* __restrict__ W_decT,
                                                   float* __restrict__ W_betaT) {
    int i = blockIdx.x * 256 + threadIdx.x;
    if (i < DECD * ATTD) {
        int l = i / ATTD, a = i % ATTD;
        W_decT[i] = W_dec[a * DECD + l];
    }
    int j = i - DECD * ATTD;
    if (j >= 0 && j < DECD * ENCD) {
        int l = j / ENCD, e = j % ENCD;
        W_betaT[j] = W_beta[e * DECD + l];
    }
}

// enc_attT[b][a][v] = bf16( enc[b][v][:] . W_enc[a][:] + b_enc[a] )  (8 acc/thread)
// Also emits enc_bf (bf16 copy of encoder) for k_awe.
__global__ __launch_bounds__(256) void k_enc_att(const float* __restrict__ enc,
                                                 const float* __restrict__ W_enc,
                                                 const float* __restrict__ b_enc,
                                                 u16* __restrict__ enc_attT,
                                                 u16* __restrict__ enc_bf) {
    __shared__ float tile[64][ENCD + 1];   // +1 pad: conflict-free column reads
    int b = blockIdx.y, v0 = blockIdx.x * 64;
    int t = threadIdx.x;
    const float* src = enc + ((size_t)b * VV + v0) * ENCD;
    u16* dstb = enc_bf + ((size_t)b * VV + v0) * ENCD;
    for (int i = t; i < 64 * ENCD; i += 256) {
        float x = src[i];
        tile[i >> 7][i & 127] = x;
        dstb[i] = to_bf16(x);
    }
    __syncthreads();
    int vl = t & 63;
    int ag = __builtin_amdgcn_readfirstlane(t >> 6);   // wave-uniform -> scalar weight loads
    for (int ao = 0; ao < 8; ao++) {
        int a0 = ag * 64 + ao * 8;
        float acc[8];
        #pragma unroll
        for (int j = 0; j < 8; j++) acc[j] = b_enc[a0 + j];
        const float* w = W_enc + (size_t)a0 * ENCD;
        for (int k = 0; k < ENCD; k++) {
            float x = tile[vl][k];
            #pragma unroll
            for (int j = 0; j < 8; j++) acc[j] = fmaf(x, w[j * ENCD + k], acc[j]);
        }
        #pragma unroll
        for (int j = 0; j < 8; j++)
            enc_attT[((size_t)b * ATTD + a0 + j) * VV + v0 + vl] = to_bf16(acc[j]);
    }
}

// mean_enc -> h0,c0 -> dec_att0, gate0, xT(emb0 + h0 rows), lengths output
__global__ __launch_bounds__(512) void k_init(const float* __restrict__ enc,
                                              const int* __restrict__ lens,
                                              const int* __restrict__ captions,
                                              const float* __restrict__ emb_W,
                                              const float* __restrict__ W_init_h,
                                              const float* __restrict__ b_init_h,
                                              const float* __restrict__ W_init_c,
                                              const float* __restrict__ b_init_c,
                                              const float* __restrict__ W_decT,
                                              const float* __restrict__ b_dec,
                                              const float* __restrict__ W_betaT,
                                              const float* __restrict__ b_beta,
                                              float* __restrict__ c0,
                                              float* __restrict__ xT,
                                              float* __restrict__ dec_att,
                                              float* __restrict__ gate,
                                              float* __restrict__ out_len) {
    __shared__ float part[512];
    __shared__ float mean[ENCD];
    __shared__ float h_s[DECD];
    int b = blockIdx.x, t = threadIdx.x;
    int e = t & 127, ch = t >> 7;
    float s = 0.f;
    const float* rowb = enc + (size_t)b * VV * ENCD;
    for (int v = ch * 512; v < ch * 512 + 512; v++) s += rowb[(size_t)v * ENCD + e];
    part[t] = s;
    __syncthreads();
    if (ch == 0) mean[e] = (part[e] + part[128 + e] + part[256 + e] + part[384 + e]) * (1.0f / VV);
    __syncthreads();
    {
        int d = t;
        float hh = b_init_h[d], cc = b_init_c[d];
        for (int k = 0; k < ENCD; k++) {
            hh = fmaf(mean[k], W_init_h[d * ENCD + k], hh);
            cc = fmaf(mean[k], W_init_c[d * ENCD + k], cc);
        }
        c0[b * DECD + d] = cc;
        h_s[d] = hh;
        xT[(384 + d) * BB + b] = hh;       // h part of unified x
    }
    __syncthreads();
    if (t < ATTD) {
        float s2 = b_dec[t];
        for (int l = 0; l < DECD; l++) s2 = fmaf(h_s[l], W_decT[l * ATTD + t], s2);
        dec_att[b * ATTD + t] = s2;
    } else if (t < ATTD + ENCD) {
        int ee = t - ATTD;
        float s2 = b_beta[ee];
        for (int l = 0; l < DECD; l++) s2 = fmaf(h_s[l], W_betaT[l * ENCD + ee], s2);
        gate[b * ENCD + ee] = sigf(s2);
    } else {
        int k = t - 384;
        int cap = captions[b * TT + 0];
        xT[k * BB + b] = emb_W[cap * EMBD + k];
        xT[(k + 128) * BB + b] = emb_W[cap * EMBD + k + 128];
    }
    if (t == 0) out_len[b] = (float)lens[b];
}

// ---------------- per-step kernels ----------------

// scores -> exp -> escore + denom. One voxel per thread; dec_att/w_full via
// uniform (scalar) loads so the inner loop is 1 vmem + 4 VALU per element.
__global__ __launch_bounds__(256) void k_scores(const u16* __restrict__ enc_attT,
                                                const float* __restrict__ dec_att,
                                                const float* __restrict__ w_full,
                                                const int* __restrict__ lens,
                                                float* __restrict__ escore,
                                                float* __restrict__ denom, int ts) {
    int b = blockIdx.y;
    if (ts >= lens[b]) return;             // lengths sorted desc
    int t = threadIdx.x;
    int v = blockIdx.x * 256 + t;
    const u16* sp = enc_attT + (size_t)b * ATTD * VV + v;
    const float* db = dec_att + b * ATTD;
    float s = 0.f;
    #pragma unroll 16
    for (int a = 0; a < ATTD; a++) {
        float x = __uint_as_float((u32)sp[(size_t)a * VV] << 16);
        s = fmaf(fmaxf(x + db[a], 0.f), w_full[a], s);   // b_full dropped (shift-invariant)
    }
    float e = __expf(s);                   // |s| < ~3, no max-subtraction needed
    escore[b * VV + v] = e;
    float ss = e;
    for (int o = 32; o > 0; o >>= 1) ss += __shfl_down(ss, o);
    __shared__ float red[4];
    if ((t & 63) == 0) red[t >> 6] = ss;
    __syncthreads();
    if (t == 0) atomicAdd(denom + ts * BB + b, red[0] + red[1] + red[2] + red[3]);
}

// alphas + awe (normalized) from bf16 encoder copy. escore via uniform s_loads.
__global__ __launch_bounds__(256) void k_awe(const u16* __restrict__ enc_bf,
                                             const float* __restrict__ escore,
                                             const float* __restrict__ denom,
                                             const int* __restrict__ lens,
                                             float* __restrict__ awe,
                                             float* __restrict__ alphas, int ts) {
    int b = blockIdx.y;
    if (ts >= lens[b]) return;
    int t = threadIdx.x;
    int v0 = blockIdx.x * 256;
    float inv = 1.0f / denom[ts * BB + b];
    alphas[((size_t)b * TT + ts) * VV + v0 + t] = escore[b * VV + v0 + t] * inv;
    int ep = t & 63, wv = t >> 6;          // e-pair 2*ep, 4 waves split v
    const u32* eb = (const u32*)(enc_bf + ((size_t)b * VV + v0) * ENCD) + ep;
    const float* es = escore + b * VV + v0;
    float a0 = 0.f, a1 = 0.f;
    #pragma unroll 8
    for (int v = wv; v < 256; v += 4) {
        u32 u = eb[(size_t)v * 64];
        float sc = es[v];                  // wave-uniform -> scalar load
        a0 = fmaf(__uint_as_float(u << 16), sc, a0);
        a1 = fmaf(__uint_as_float(u & 0xffff0000u), sc, a1);
    }
    __shared__ float red[4][ENCD];
    red[wv][2 * ep] = a0;
    red[wv][2 * ep + 1] = a1;
    __syncthreads();
    if (t < ENCD) {
        float r = (red[0][t] + red[1][t] + red[2][t] + red[3][t]) * inv;
        atomicAdd(awe + ((size_t)ts * BB + b) * ENCD + t, r);
    }
}

// gates_part[kc][b][g] partial GEMM: unified K = [emb(256) | gated awe(128) | h(512)]
// lanes = b; weight rows forced scalar via readfirstlane.
__global__ __launch_bounds__(256) void k_lstm(const float* __restrict__ xT,
                                              const float* __restrict__ awe,
                                              const float* __restrict__ gate,
                                              const float* __restrict__ W_ih,
                                              const float* __restrict__ W_hh,
                                              const float* __restrict__ b_ih,
                                              const float* __restrict__ b_hh,
                                              float* __restrict__ gates_part, int ts) {
    __shared__ float gawe[BB][ENCD + 1];   // pad: lane-major reads conflict-free
    int gt = blockIdx.x, kc = blockIdx.y;
    int lane = threadIdx.x & 63, wv = threadIdx.x >> 6;
    int gbase = gt * 32 + wv * 8;
    int gb = __builtin_amdgcn_readfirstlane(gbase);   // scalar weight addressing
    int k0 = kc * 128;
    float acc[8];
    #pragma unroll
    for (int j = 0; j < 8; j++)
        acc[j] = (kc == 0) ? (b_ih[gb + j] + b_hh[gb + j]) : 0.f;
    if (kc == 2) {                          // gated-awe columns 256..383 (awe pre-normalized)
        for (int i = threadIdx.x; i < BB * ENCD; i += 256) {
            int bb = i >> 7, ee = i & 127;
            gawe[bb][ee] = gate[bb * ENCD + ee] * awe[((size_t)ts * BB + bb) * ENCD + ee];
        }
        __syncthreads();
        for (int kk = 0; kk < ENCD; kk++) {
            float xv = gawe[lane][kk];
            #pragma unroll
            for (int j = 0; j < 8; j++)
                acc[j] = fmaf(xv, W_ih[(gb + j) * 384 + 256 + kk], acc[j]);
        }
    } else if (kc < 2) {                    // emb columns 0..255
        for (int kk = 0; kk < 128; kk++) {
            float xv = xT[(k0 + kk) * BB + lane];
            #pragma unroll
            for (int j = 0; j < 8; j++)
                acc[j] = fmaf(xv, W_ih[(gb + j) * 384 + k0 + kk], acc[j]);
        }
    } else {                                // h columns (W_hh cols 0..511)
        const float* Wh = W_hh + (k0 - 384);
        for (int kk = 0; kk < 128; kk++) {
            float xv = xT[(k0 + kk) * BB + lane];
            #pragma unroll
            for (int j = 0; j < 8; j++)
                acc[j] = fmaf(xv, Wh[(gb + j) * DECD + kk], acc[j]);
        }
    }
    // [kc][b][g]: scattered writes here, fully coalesced reads in k_cell
    float4* o4 = (float4*)(gates_part + ((size_t)kc * BB + lane) * 2048 + gbase);
    o4[0] = make_float4(acc[0], acc[1], acc[2], acc[3]);
    o4[1] = make_float4(acc[4], acc[5], acc[6], acc[7]);
}

// cell update + predictions + next-step dec_att/gate/emb staging
__global__ __launch_bounds__(512) void k_cell(const float* __restrict__ gates_part,
                                              const int* __restrict__ lens,
                                              const int* __restrict__ captions,
                                              const float* __restrict__ emb_W,
                                              const float* __restrict__ W_final,
                                              const float* __restrict__ b_final,
                                              const float* __restrict__ W_decT,
                                              const float* __restrict__ b_dec,
                                              const float* __restrict__ W_betaT,
                                              const float* __restrict__ b_beta,
                                              float* __restrict__ c0,
                                              float* __restrict__ c1,
                                              float* __restrict__ xT,
                                              float* __restrict__ dec_att,
                                              float* __restrict__ gate,
                                              float* __restrict__ preds, int ts) {
    int b = blockIdx.x;
    if (ts >= lens[b]) return;             // masked rows: state stays stale = correct
    __shared__ float h_s[DECD];
    int t = threadIdx.x;
    const float* cin = (ts & 1) ? c1 : c0;
    float*       cout = (ts & 1) ? c0 : c1;
    {
        float gi = 0.f, gf = 0.f, gg = 0.f, go = 0.f;
        #pragma unroll
        for (int kc = 0; kc < 7; kc++) {
            const float* gp = gates_part + ((size_t)kc * BB + b) * 2048;
            gi += gp[t]; gf += gp[512 + t]; gg += gp[1024 + t]; go += gp[1536 + t];
        }
        gi = sigf(gi); gf = sigf(gf); go = sigf(go); gg = tanhf(gg);
        float cn = fmaf(gf, cin[b * DECD + t], gi * gg);
        float hn = go * tanhf(cn);
        cout[b * DECD + t] = cn;
        h_s[t] = hn;
        xT[(384 + t) * BB + b] = hn;
    }
    __syncthreads();
    int lane = t & 63, wv = t >> 6;
    for (int j = wv; j < NVOCAB; j += 8) {  // predictions, all 8 waves
        float s = 0.f;
        #pragma unroll
        for (int i = 0; i < 8; i++)
            s = fmaf(h_s[lane + 64 * i], W_final[j * DECD + lane + 64 * i], s);
        for (int o = 32; o > 0; o >>= 1) s += __shfl_down(s, o);
        if (lane == 0) preds[((size_t)b * TT + ts) * NVOCAB + j] = s + b_final[j];
    }
    if (t < ATTD) {                         // next-step dec_att
        float s = b_dec[t];
        for (int l = 0; l < DECD; l++) s = fmaf(h_s[l], W_decT[l * ATTD + t], s);
        dec_att[b * ATTD + t] = s;
    } else if (t < ATTD + ENCD) {           // next-step gate
        int ee = t - ATTD;
        float s = b_beta[ee];
        for (int l = 0; l < DECD; l++) s = fmaf(h_s[l], W_betaT[l * ENCD + ee], s);
        gate[b * ENCD + ee] = sigf(s);
    } else if (ts + 1 < TT) {               // next-step embedding
        int k = t - 384;
        int cap = captions[b * TT + ts + 1];
        xT[k * BB + b] = emb_W[cap * EMBD + k];
        xT[(k + 128) * BB + b] = emb_W[cap * EMBD + k + 128];
    }
}

extern "C" void kernel_launch(void* const* d_in, const int* in_sizes, int n_in,
                              void* d_out, int out_size, void* d_ws, size_t ws_size,
                              hipStream_t stream) {
    const float* enc      = (const float*)d_in[0];
    const int*   captions = (const int*)d_in[1];
    const int*   lens     = (const int*)d_in[2];
    const float* emb_W    = (const float*)d_in[3];
    const float* W_enc    = (const float*)d_in[4];
    const float* b_enc    = (const float*)d_in[5];
    const float* W_dec    = (const float*)d_in[6];
    const float* b_dec    = (const float*)d_in[7];
    const float* w_full   = (const float*)d_in[8];
    // d_in[9] b_full: unused — softmax is shift-invariant
    const float* W_ih     = (const float*)d_in[10];
    const float* b_ih     = (const float*)d_in[11];
    const float* W_hh     = (const float*)d_in[12];
    const float* b_hh     = (const float*)d_in[13];
    const float* W_init_h = (const float*)d_in[14];
    const float* b_init_h = (const float*)d_in[15];
    const float* W_init_c = (const float*)d_in[16];
    const float* b_init_c = (const float*)d_in[17];
    const float* W_beta   = (const float*)d_in[18];
    const float* b_beta   = (const float*)d_in[19];
    const float* W_final  = (const float*)d_in[20];
    const float* b_final  = (const float*)d_in[21];

    float* preds   = (float*)d_out;                      // [B][T][VOCAB]
    float* alphas  = preds + (size_t)BB * TT * NVOCAB;   // [B][T][V]
    float* out_len = alphas + (size_t)BB * TT * VV;      // [B] (as float)

    char* ws = (char*)d_ws;
    size_t off = 0;
    auto alloc = [&](size_t bytes) {
        char* p = ws + off;
        off += (bytes + 255) & ~(size_t)255;
        return p;
    };
    u16*   enc_attT   = (u16*)  alloc((size_t)BB * ATTD * VV * sizeof(u16));   // 67 MB
    u16*   enc_bf     = (u16*)  alloc((size_t)BB * VV * ENCD * sizeof(u16));   // 33.5 MB
    float* escore     = (float*)alloc((size_t)BB * VV * sizeof(float));
    char*  zbase      = ws + off;                                              // zeroed region
    float* denom      = (float*)alloc((size_t)TT * BB * sizeof(float));
    float* awe        = (float*)alloc((size_t)TT * BB * ENCD * sizeof(float));
    size_t zbytes     = (size_t)((ws + off) - zbase);
    float* dec_att    = (float*)alloc((size_t)BB * ATTD * sizeof(float));
    float* gate       = (float*)alloc((size_t)BB * ENCD * sizeof(float));
    float* xT         = (float*)alloc((size_t)896 * BB * sizeof(float));
    float* gates_part = (float*)alloc((size_t)7 * BB * 2048 * sizeof(float));
    float* c0         = (float*)alloc((size_t)BB * DECD * sizeof(float));
    float* c1         = (float*)alloc((size_t)BB * DECD * sizeof(float));
    float* W_decT     = (float*)alloc((size_t)DECD * ATTD * sizeof(float));
    float* W_betaT    = (float*)alloc((size_t)DECD * ENCD * sizeof(float));

    // masked (b,t) outputs must be exactly 0; atomic targets must start at 0
    hipMemsetAsync(d_out, 0, (size_t)out_size * sizeof(float), stream);
    hipMemsetAsync(zbase, 0, zbytes, stream);

    k_transpose<<<768, 256, 0, stream>>>(W_dec, W_beta, W_decT, W_betaT);
    k_enc_att<<<dim3(VV / 64, BB), 256, 0, stream>>>(enc, W_enc, b_enc, enc_attT, enc_bf);
    k_init<<<BB, 512, 0, stream>>>(enc, lens, captions, emb_W, W_init_h, b_init_h,
                                   W_init_c, b_init_c, W_decT, b_dec, W_betaT, b_beta,
                                   c0, xT, dec_att, gate, out_len);

    for (int t = 0; t < TT; t++) {
        k_scores<<<dim3(8, BB), 256, 0, stream>>>(enc_attT, dec_att, w_full, lens,
                                                  escore, denom, t);
        k_awe<<<dim3(8, BB), 256, 0, stream>>>(enc_bf, escore, denom, lens, awe, alphas, t);
        k_lstm<<<dim3(64, 7), 256, 0, stream>>>(xT, awe, gate, W_ih, W_hh, b_ih, b_hh,
                                                gates_part, t);
        k_cell<<<BB, 512, 0, stream>>>(gates_part, lens, captions, emb_W, W_final, b_final,
                                       W_decT, b_dec, W_betaT, b_beta, c0, c1, xT, dec_att,
                                       gate, preds, t);
    }
}